// Round 6
// baseline (144.105 us; speedup 1.0000x reference)
//
#include <hip/hip_runtime.h>

#define BB 64
#define TT 4096
#define CC 51
#define DD 64
#define LN_EPS 1e-5f

typedef __attribute__((ext_vector_type(16))) int i32x16;
typedef __attribute__((ext_vector_type(2)))  int i32x2;
typedef __attribute__((ext_vector_type(4)))  float f32x4;

// DPP control codes (verified R3-R5)
#define DPP_QP_1032   0xB1
#define DPP_QP_2301   0x4E
#define DPP_ROW_HMIRR 0x141
#define DPP_ROW_MIRR  0x140

__device__ __forceinline__ float dpp_add(float v, int tag) {
  int t;
  switch (tag) {
    case 0: t = __builtin_amdgcn_update_dpp(0, __float_as_int(v), DPP_QP_1032,   0xF, 0xF, true); break;
    case 1: t = __builtin_amdgcn_update_dpp(0, __float_as_int(v), DPP_QP_2301,   0xF, 0xF, true); break;
    case 2: t = __builtin_amdgcn_update_dpp(0, __float_as_int(v), DPP_ROW_HMIRR, 0xF, 0xF, true); break;
    default: t = __builtin_amdgcn_update_dpp(0, __float_as_int(v), DPP_ROW_MIRR, 0xF, 0xF, true); break;
  }
  return v + __int_as_float(t);
}
__device__ __forceinline__ float allsum16(float v) {
  v = dpp_add(v, 0); v = dpp_add(v, 1); v = dpp_add(v, 2); v = dpp_add(v, 3);
  return v;
}
__device__ __forceinline__ float allsum64(float v) {
  v = allsum16(v);
  v += __shfl_xor(v, 16, 64);
  v += __shfl_xor(v, 32, 64);
  return v;
}

// One row: x row in SGPRs via s_load (wave-uniform base), 51 v_fmac with SGPR
// src0, LN across the 64 lanes, NT store. tm rows skip everything (uniform branch).
template <int R>
__device__ __forceinline__ void doRow(const float* xb, int tm,
                                      const float (&wq)[CC], float bias,
                                      float gL, float bL, float cons,
                                      float* outRow, int L) {
  if (tm) {
    __builtin_nontemporal_store(cons, outRow + R * DD + L);
    return;
  }
  i32x16 A, B, C; i32x2 D2; int E;
  asm volatile(
      "s_load_dwordx16 %0, %5, %c6\n\t"
      "s_load_dwordx16 %1, %5, %c7\n\t"
      "s_load_dwordx16 %2, %5, %c8\n\t"
      "s_load_dwordx2  %3, %5, %c9\n\t"
      "s_load_dword    %4, %5, %c10"
      : "=s"(A), "=s"(B), "=s"(C), "=s"(D2), "=s"(E)
      : "s"(xb), "i"(R * 204), "i"(R * 204 + 64), "i"(R * 204 + 128),
        "i"(R * 204 + 192), "i"(R * 204 + 200));
  asm volatile("s_waitcnt lgkmcnt(0)"
               : "+s"(A), "+s"(B), "+s"(C), "+s"(D2), "+s"(E));
  float q0 = bias, q1 = 0.0f, q2 = 0.0f, q3 = 0.0f;
#define FM(c, S) { const float xs_ = __int_as_float(S);          \
    if      (((c) & 3) == 0) q0 = fmaf(xs_, wq[c], q0);           \
    else if (((c) & 3) == 1) q1 = fmaf(xs_, wq[c], q1);           \
    else if (((c) & 3) == 2) q2 = fmaf(xs_, wq[c], q2);           \
    else                     q3 = fmaf(xs_, wq[c], q3); }
  FM(0,A[0])  FM(1,A[1])  FM(2,A[2])  FM(3,A[3])
  FM(4,A[4])  FM(5,A[5])  FM(6,A[6])  FM(7,A[7])
  FM(8,A[8])  FM(9,A[9])  FM(10,A[10]) FM(11,A[11])
  FM(12,A[12]) FM(13,A[13]) FM(14,A[14]) FM(15,A[15])
  FM(16,B[0])  FM(17,B[1])  FM(18,B[2])  FM(19,B[3])
  FM(20,B[4])  FM(21,B[5])  FM(22,B[6])  FM(23,B[7])
  FM(24,B[8])  FM(25,B[9])  FM(26,B[10]) FM(27,B[11])
  FM(28,B[12]) FM(29,B[13]) FM(30,B[14]) FM(31,B[15])
  FM(32,C[0])  FM(33,C[1])  FM(34,C[2])  FM(35,C[3])
  FM(36,C[4])  FM(37,C[5])  FM(38,C[6])  FM(39,C[7])
  FM(40,C[8])  FM(41,C[9])  FM(42,C[10]) FM(43,C[11])
  FM(44,C[12]) FM(45,C[13]) FM(46,C[14]) FM(47,C[15])
  FM(48,D2[0]) FM(49,D2[1]) FM(50,E)
#undef FM
  const float o  = (q0 + q1) + (q2 + q3);
  const float su = allsum64(o);
  const float sq = allsum64(o * o);
  const float mu = su * (1.0f / 64.0f);
  const float vr = fmaf(-mu, mu, sq * (1.0f / 64.0f));
  const float rs = rsqrtf(vr + LN_EPS);
  const float val = fmaf((o - mu) * rs, gL, bL);
  __builtin_nontemporal_store(val, outRow + R * DD + L);
}

// ---- row-per-iteration VALU kernel: lane = d, 32 rows/wave, no LDS/barriers ----
__global__ __launch_bounds__(256, 4)
void ipmask_valu(const float* __restrict__ x, const float* __restrict__ W,
                 const float* __restrict__ Wm,
                 const float* __restrict__ gamma, const float* __restrict__ beta,
                 const int* __restrict__ tmask, const int* __restrict__ smask,
                 float* __restrict__ out) {
  const int t = threadIdx.x, L = t & 63, w = t >> 6;
  const int gwU = __builtin_amdgcn_readfirstlane((blockIdx.x << 2) + w); // 8192 waves
  const int rowBase = gwU << 5;                 // 32 rows per wave
  const int b = rowBase >> 12;                  // 4096 rows per b
  const int* smB = smask + b * CC;
  const float* xb = x + (size_t)rowBase * CC;

  // ---- prime L2 with this wave's x slab (32 rows x 204 B = 6528 B) ----
  f32x4 p0, p1, p2, p3, p4, p5, p6;
  const char* xc = (const char*)xb;
  __builtin_memcpy(&p0, xc + 0 * 1024 + L * 16, 16);
  __builtin_memcpy(&p1, xc + 1 * 1024 + L * 16, 16);
  __builtin_memcpy(&p2, xc + 2 * 1024 + L * 16, 16);
  __builtin_memcpy(&p3, xc + 3 * 1024 + L * 16, 16);
  __builtin_memcpy(&p4, xc + 4 * 1024 + L * 16, 16);
  __builtin_memcpy(&p5, xc + 5 * 1024 + L * 16, 16);
  __builtin_memcpy(&p6, xc + 5504 + L * 16, 16);        // tail, ends at 6528

  // ---- per-wave preamble: masked W column (51 VGPRs), bias, Wm colsum ----
  float wq[CC];
  float bias = 0.0f, f = 0.0f;
#pragma unroll
  for (int c = 0; c < CC; ++c) {
    const float wv  = W[c * DD + L];    // coalesced 256B per c, L1/L2-hot
    const float wmv = Wm[c * DD + L];
    const int   s   = smB[c];           // uniform addr -> scalar load
    wq[c] = s ? 0.0f : wv;
    bias  = fmaf((float)s, wmv, bias);
    f += wmv;
  }
  const float gL = gamma[L], bL = beta[L];
  float cons;
  {
    const float s1 = allsum64(f);
    const float s2 = allsum64(f * f);
    const float mu = s1 * (1.0f / 64.0f);
    const float vr = fmaf(-mu, mu, s2 * (1.0f / 64.0f));
    const float rs = rsqrtf(vr + LN_EPS);
    cons = fmaf((f - mu) * rs, gL, bL);
  }
  // retire the prime loads here (their vmcnt wait overlaps the preamble)
  asm volatile("" :: "v"(p0), "v"(p1), "v"(p2), "v"(p3), "v"(p4), "v"(p5), "v"(p6));

  float* outRow = out + (size_t)rowBase * DD;

  i32x16 tmv;
  asm volatile("s_load_dwordx16 %0, %1, 0x0\n\ts_waitcnt lgkmcnt(0)"
               : "=s"(tmv) : "s"(tmask + rowBase));
  doRow<0>(xb, tmv[0],  wq, bias, gL, bL, cons, outRow, L);
  doRow<1>(xb, tmv[1],  wq, bias, gL, bL, cons, outRow, L);
  doRow<2>(xb, tmv[2],  wq, bias, gL, bL, cons, outRow, L);
  doRow<3>(xb, tmv[3],  wq, bias, gL, bL, cons, outRow, L);
  doRow<4>(xb, tmv[4],  wq, bias, gL, bL, cons, outRow, L);
  doRow<5>(xb, tmv[5],  wq, bias, gL, bL, cons, outRow, L);
  doRow<6>(xb, tmv[6],  wq, bias, gL, bL, cons, outRow, L);
  doRow<7>(xb, tmv[7],  wq, bias, gL, bL, cons, outRow, L);
  doRow<8>(xb, tmv[8],  wq, bias, gL, bL, cons, outRow, L);
  doRow<9>(xb, tmv[9],  wq, bias, gL, bL, cons, outRow, L);
  doRow<10>(xb, tmv[10], wq, bias, gL, bL, cons, outRow, L);
  doRow<11>(xb, tmv[11], wq, bias, gL, bL, cons, outRow, L);
  doRow<12>(xb, tmv[12], wq, bias, gL, bL, cons, outRow, L);
  doRow<13>(xb, tmv[13], wq, bias, gL, bL, cons, outRow, L);
  doRow<14>(xb, tmv[14], wq, bias, gL, bL, cons, outRow, L);
  doRow<15>(xb, tmv[15], wq, bias, gL, bL, cons, outRow, L);
  asm volatile("s_load_dwordx16 %0, %1, 0x40\n\ts_waitcnt lgkmcnt(0)"
               : "=s"(tmv) : "s"(tmask + rowBase));
  doRow<16>(xb, tmv[0],  wq, bias, gL, bL, cons, outRow, L);
  doRow<17>(xb, tmv[1],  wq, bias, gL, bL, cons, outRow, L);
  doRow<18>(xb, tmv[2],  wq, bias, gL, bL, cons, outRow, L);
  doRow<19>(xb, tmv[3],  wq, bias, gL, bL, cons, outRow, L);
  doRow<20>(xb, tmv[4],  wq, bias, gL, bL, cons, outRow, L);
  doRow<21>(xb, tmv[5],  wq, bias, gL, bL, cons, outRow, L);
  doRow<22>(xb, tmv[6],  wq, bias, gL, bL, cons, outRow, L);
  doRow<23>(xb, tmv[7],  wq, bias, gL, bL, cons, outRow, L);
  doRow<24>(xb, tmv[8],  wq, bias, gL, bL, cons, outRow, L);
  doRow<25>(xb, tmv[9],  wq, bias, gL, bL, cons, outRow, L);
  doRow<26>(xb, tmv[10], wq, bias, gL, bL, cons, outRow, L);
  doRow<27>(xb, tmv[11], wq, bias, gL, bL, cons, outRow, L);
  doRow<28>(xb, tmv[12], wq, bias, gL, bL, cons, outRow, L);
  doRow<29>(xb, tmv[13], wq, bias, gL, bL, cons, outRow, L);
  doRow<30>(xb, tmv[14], wq, bias, gL, bL, cons, outRow, L);
  doRow<31>(xb, tmv[15], wq, bias, gL, bL, cons, outRow, L);
}

extern "C" void kernel_launch(void* const* d_in, const int* in_sizes, int n_in,
                              void* d_out, int out_size, void* d_ws, size_t ws_size,
                              hipStream_t stream) {
  const float* x     = (const float*)d_in[0];
  const float* W     = (const float*)d_in[1];
  const float* Wm    = (const float*)d_in[2];
  const float* gamma = (const float*)d_in[3];
  const float* beta  = (const float*)d_in[4];
  const int*   tmask = (const int*)d_in[5];
  const int*   smask = (const int*)d_in[6];
  float* out = (float*)d_out;

  ipmask_valu<<<dim3(2048), dim3(256), 0, stream>>>(
      x, W, Wm, gamma, beta, tmask, smask, out);
}